// Round 5
// baseline (771.503 us; speedup 1.0000x reference)
//
#include <hip/hip_runtime.h>

#define NACT 200000
#define MPAD 200064          // ceil(NACT/128)*128
#define NBLK 1563            // MPAD/128
#define KOFF 27
#define GSTR 32              // G2 row stride in ints (27 padded to 32)

#define SCAT_B 21094         // ceil(27*200000/256)
#define CAST_B 25001         // ceil((200000+1)*32/256)
#define PREPW_B 1728         // 27*16384/256

typedef __bf16 bf16x8 __attribute__((ext_vector_type(8)));
typedef __bf16 bf16x4 __attribute__((ext_vector_type(4)));
typedef float f32x4 __attribute__((ext_vector_type(4)));

__device__ __forceinline__ void async_load16(const void* g, void* l) {
  __builtin_amdgcn_global_load_lds(
      (__attribute__((address_space(1))) void*)g,
      (__attribute__((address_space(3))) void*)l, 16, 0, 0);
}

// ---------------- fused prep: rulebook scatter + feature cast + W transpose -------
// G2 pre-filled with 0x7F7F7F7F sentinel via hipMemsetAsync; GEMM clamps to zero-row.
// Last block zeroes the BN-stats accumulators (GEMM epilogues atomicAdd into them).
__global__ void prep_all(const int* __restrict__ ii, const int* __restrict__ oi,
                         int* __restrict__ G2,
                         const float* __restrict__ F, __bf16* __restrict__ X,
                         const float* __restrict__ W1, const float* __restrict__ W2,
                         __bf16* __restrict__ T1, __bf16* __restrict__ T2,
                         float* __restrict__ st) {
  int b = blockIdx.x;
  if (b < SCAT_B) {
    int i = b * 256 + threadIdx.x;
    if (i < KOFF * NACT) {
      int o = oi[i];
      if (o < NACT) G2[o * GSTR + (i / NACT)] = ii[i];  // skip pads (o==NACT)
    }
  } else if (b < SCAT_B + CAST_B) {
    int i = (b - SCAT_B) * 256 + threadIdx.x;
    if (i < (NACT + 1) * 32) {
      float4 v = (i < NACT * 32) ? ((const float4*)F)[i] : make_float4(0.f, 0.f, 0.f, 0.f);
      bf16x4 o = {(__bf16)v.x, (__bf16)v.y, (__bf16)v.z, (__bf16)v.w};
      *(bf16x4*)(X + (i << 2)) = o;
    }
  } else if (b < SCAT_B + CAST_B + PREPW_B) {
    int i = (b - SCAT_B - CAST_B) * 256 + threadIdx.x;   // WT[k][n][c] = W[k][c][n]
    int k = i >> 14, r = i & 16383, n = r >> 7, c = r & 127;
    int src = (k << 14) + (c << 7) + n;
    T1[i] = (__bf16)W1[src];
    T2[i] = (__bf16)W2[src];
  } else {
    st[threadIdx.x] = 0.f;          // conv1 stats
    st[256 + threadIdx.x] = 0.f;    // conv2 stats
  }
}

// ---------------- gather-GEMM: Y[m,:] = sum_k X[G2[m][k],:] @ W[k] ----------------
// 128x128 tile, 4 waves (2x2 of 64x64), BK=64, XOR-8 LDS swizzle (R2 structure —
// best measured: 177us/43% MFMA; R3 direct-global B and R4 fat tile both regressed).
// New: G2 is row-major [m][32] -> per-block G working set 16KB = L1-resident after
// kk=0; next-kk indices register-prefetched alongside stage-0 async loads.
// Epilogue atomicAdds BN-stats partials straight into st[256].
__global__ __launch_bounds__(256, 4) void gemm_gather(
    const __bf16* __restrict__ X,   // [NACT+1][128], row NACT = 0
    const __bf16* __restrict__ WT,  // [27][128][128] : WT[k][n][c]
    const int* __restrict__ G2,     // [MPAD][32], sentinel-clamped
    __bf16* __restrict__ Y,         // [MPAD][128] bf16
    float* __restrict__ st)         // [256]: sum[c], sumsq[c] (pre-zeroed)
{
  __shared__ __bf16 Alds[128 * 64];   // 16 KB
  __shared__ __bf16 Blds[128 * 64];   // 16 KB
  const int t = threadIdx.x;
  const int lane = t & 63;
  const int w = t >> 6;
  const int wm = (w & 1) << 6;
  const int wn = (w >> 1) << 6;
  const int m_base = blockIdx.x << 7;
  const int r0 = t >> 3;   // staging row group 0..31
  const int scb = t & 7;   // lds 16B-chunk slot within row
  const int l15 = lane & 15;
  const int q4 = lane >> 4;

  f32x4 acc[4][4];
#pragma unroll
  for (int i = 0; i < 4; ++i)
#pragma unroll
    for (int j = 0; j < 4; ++j) acc[i][j] = (f32x4){0.f, 0.f, 0.f, 0.f};

  const int* gbase = G2 + (size_t)(m_base + r0) * GSTR;
  int rowN[4];
#pragma unroll
  for (int j = 0; j < 4; ++j) rowN[j] = gbase[j * 32 * GSTR];   // kk = 0

  for (int kk = 0; kk < KOFF; ++kk) {
    int rowA[4];
#pragma unroll
    for (int j = 0; j < 4; ++j)
      rowA[j] = rowN[j] < NACT ? rowN[j] : NACT;   // clamp sentinel/pads to zero-row
    const __bf16* wb = WT + (kk << 14);
#pragma unroll
    for (int s = 0; s < 2; ++s) {
      const int c0 = s << 6;
      __syncthreads();   // previous compute finished before LDS overwrite
#pragma unroll
      for (int j = 0; j < 4; ++j) {
        const int r = r0 + j * 32;
        const int gcb = scb ^ (r & 7);   // XOR-swizzle: slot scb <- global chunk gcb
        async_load16(X + (rowA[j] << 7) + c0 + (gcb << 3), &Alds[(((r << 3) + scb) << 3)]);
        async_load16(wb + (r << 7) + c0 + (gcb << 3), &Blds[(((r << 3) + scb) << 3)]);
      }
      if (s == 0 && kk + 1 < KOFF) {     // prefetch next-kk indices (L1-hot lines)
#pragma unroll
        for (int j = 0; j < 4; ++j) rowN[j] = gbase[j * 32 * GSTR + kk + 1];
      }
      __syncthreads();   // vmcnt(0) drain for global_load_lds
#pragma unroll
      for (int ks = 0; ks < 2; ++ks) {
        bf16x8 af[4], bfr[4];
        const int cb0 = (ks << 2) + q4;
#pragma unroll
        for (int mi = 0; mi < 4; ++mi) {
          const int r = wm + mi * 16 + l15;
          af[mi] = *(const bf16x8*)&Alds[(((r << 3) + (cb0 ^ (r & 7))) << 3)];
        }
#pragma unroll
        for (int ni = 0; ni < 4; ++ni) {
          const int r = wn + ni * 16 + l15;
          bfr[ni] = *(const bf16x8*)&Blds[(((r << 3) + (cb0 ^ (r & 7))) << 3)];
        }
#pragma unroll
        for (int mi = 0; mi < 4; ++mi)
#pragma unroll
          for (int ni = 0; ni < 4; ++ni)
            acc[mi][ni] = __builtin_amdgcn_mfma_f32_16x16x32_bf16(
                af[mi], bfr[ni], acc[mi][ni], 0, 0, 0);
      }
    }
  }

  // ---- epilogue 1: bf16 Y stores (C/D layout: col=lane&15, row=quad*4+reg) ----
#pragma unroll
  for (int mi = 0; mi < 4; ++mi) {
#pragma unroll
    for (int ni = 0; ni < 4; ++ni) {
      const int col = wn + ni * 16 + l15;
#pragma unroll
      for (int rg = 0; rg < 4; ++rg) {
        const int row = m_base + wm + mi * 16 + (q4 << 2) + rg;
        Y[(row << 7) + col] = (__bf16)acc[mi][ni][rg];
      }
    }
  }

  // ---- epilogue 2: BN stats partials -> device atomicAdd (padding rows are 0) ----
  float s[4], s2[4];
#pragma unroll
  for (int ni = 0; ni < 4; ++ni) {
    float a = 0.f, b = 0.f;
#pragma unroll
    for (int mi = 0; mi < 4; ++mi)
#pragma unroll
      for (int rg = 0; rg < 4; ++rg) {
        float v = acc[mi][ni][rg];
        a += v; b += v * v;
      }
    s[ni] = a; s2[ni] = b;
  }
#pragma unroll
  for (int ni = 0; ni < 4; ++ni) {
    s[ni]  += __shfl_xor(s[ni], 16);  s[ni]  += __shfl_xor(s[ni], 32);
    s2[ni] += __shfl_xor(s2[ni], 16); s2[ni] += __shfl_xor(s2[ni], 32);
  }
  float* sc = (float*)Alds;   // 512 floats scratch
  __syncthreads();
  if (q4 == 0) {
#pragma unroll
    for (int ni = 0; ni < 4; ++ni) {
      sc[(w << 6) + ni * 16 + l15]       = s[ni];
      sc[256 + (w << 6) + ni * 16 + l15] = s2[ni];
    }
  }
  __syncthreads();
  {
    const int kind = t >> 7, col = t & 127;
    const int w1 = (col >> 6) << 1;
    const float v = sc[kind * 256 + (w1 << 6) + (col & 63)] +
                    sc[kind * 256 + ((w1 + 1) << 6) + (col & 63)];
    atomicAdd(&st[t], v);
  }
}

// ---------------- fused BN consumers (coeffs recomputed per thread from st) -------
__device__ __forceinline__ void bn_make(const float* __restrict__ st,
                                        const float* __restrict__ gamma,
                                        const float* __restrict__ beta,
                                        int cg, float* sc, float* sh) {
#pragma unroll
  for (int e = 0; e < 8; ++e) {
    int c = cg + e;
    float m = st[c] * (1.f / NACT);
    float v = st[128 + c] * (1.f / NACT) - m * m;
    float s = gamma[c] * rsqrtf(v + 1e-4f);
    sc[e] = s;
    sh[e] = beta[c] - m * s;
  }
}

__global__ void bn_relu_cast(const __bf16* __restrict__ Y, const float* __restrict__ st,
                             const float* __restrict__ gamma, const float* __restrict__ beta,
                             __bf16* __restrict__ X2) {
  int i = blockIdx.x * 256 + threadIdx.x;   // 8-elem chunks, (NACT+1)*16
  if (i >= (NACT + 1) * 16) return;
  bf16x8 o;
  if (i < NACT * 16) {
    int cg = (i & 15) << 3;
    float sc[8], sh[8];
    bn_make(st, gamma, beta, cg, sc, sh);
    bf16x8 v = ((const bf16x8*)Y)[i];
#pragma unroll
    for (int e = 0; e < 8; ++e) {
      float x = fmaf((float)v[e], sc[e], sh[e]);
      o[e] = (__bf16)fmaxf(x, 0.f);
    }
  } else {
#pragma unroll
    for (int e = 0; e < 8; ++e) o[e] = (__bf16)0.f;   // keep zero-row zero
  }
  ((bf16x8*)X2)[i] = o;
}

__global__ void bn_add_relu(const __bf16* __restrict__ Y, const float* __restrict__ st,
                            const float* __restrict__ gamma, const float* __restrict__ beta,
                            const __bf16* __restrict__ Xr, float* __restrict__ O) {
  int i = blockIdx.x * 256 + threadIdx.x;   // 8-elem chunks, NACT*16
  if (i >= NACT * 16) return;
  int cg = (i & 15) << 3;
  float sc[8], sh[8];
  bn_make(st, gamma, beta, cg, sc, sh);
  bf16x8 v = ((const bf16x8*)Y)[i];
  bf16x8 f = ((const bf16x8*)Xr)[i];
  float4 o0, o1;
  o0.x = fmaxf(fmaf((float)v[0], sc[0], sh[0]) + (float)f[0], 0.f);
  o0.y = fmaxf(fmaf((float)v[1], sc[1], sh[1]) + (float)f[1], 0.f);
  o0.z = fmaxf(fmaf((float)v[2], sc[2], sh[2]) + (float)f[2], 0.f);
  o0.w = fmaxf(fmaf((float)v[3], sc[3], sh[3]) + (float)f[3], 0.f);
  o1.x = fmaxf(fmaf((float)v[4], sc[4], sh[4]) + (float)f[4], 0.f);
  o1.y = fmaxf(fmaf((float)v[5], sc[5], sh[5]) + (float)f[5], 0.f);
  o1.z = fmaxf(fmaf((float)v[6], sc[6], sh[6]) + (float)f[6], 0.f);
  o1.w = fmaxf(fmaf((float)v[7], sc[7], sh[7]) + (float)f[7], 0.f);
  ((float4*)O)[2 * i] = o0;
  ((float4*)O)[2 * i + 1] = o1;
}

// ---------------- launcher ----------------
extern "C" void kernel_launch(void* const* d_in, const int* in_sizes, int n_in,
                              void* d_out, int out_size, void* d_ws, size_t ws_size,
                              hipStream_t stream) {
  const float* features = (const float*)d_in[0];
  const float* W1       = (const float*)d_in[1];
  const float* gamma1   = (const float*)d_in[2];
  const float* beta1    = (const float*)d_in[3];
  const float* W2       = (const float*)d_in[4];
  const float* gamma2   = (const float*)d_in[5];
  const float* beta2    = (const float*)d_in[6];
  const int* in_idx     = (const int*)d_in[7];
  const int* out_idx    = (const int*)d_in[8];

  char* ws = (char*)d_ws;
  size_t off = 0;
  int*    G2  = (int*)(ws + off);    off += (size_t)MPAD * GSTR * 4;          // 25.6 MB
  __bf16* X1  = (__bf16*)(ws + off); off += (size_t)(NACT + 1) * 128 * 2;     // 51.2 MB
  __bf16* X2  = (__bf16*)(ws + off); off += (size_t)(NACT + 1) * 128 * 2;     // 51.2 MB
  __bf16* T1  = (__bf16*)(ws + off); off += (size_t)KOFF * 128 * 128 * 2;     // 0.88 MB
  __bf16* T2  = (__bf16*)(ws + off); off += (size_t)KOFF * 128 * 128 * 2;     // 0.88 MB
  __bf16* Y   = (__bf16*)(ws + off); off += (size_t)MPAD * 128 * 2;           // 51.2 MB
  float*  st  = (float*)(ws + off);  off += 4096;   // stats1 @0, stats2 @256

  hipMemsetAsync(G2, 0x7F, (size_t)MPAD * GSTR * 4, stream);  // sentinel > NACT

  prep_all<<<SCAT_B + CAST_B + PREPW_B + 1, 256, 0, stream>>>(
      in_idx, out_idx, G2, features, X1, W1, W2, T1, T2, st);

  gemm_gather<<<NBLK, 256, 0, stream>>>(X1, T1, G2, Y, st);
  bn_relu_cast<<<((NACT + 1) * 16 + 255) / 256, 256, 0, stream>>>(Y, st, gamma1, beta1, X2);

  gemm_gather<<<NBLK, 256, 0, stream>>>(X2, T2, G2, Y, st + 256);
  bn_add_relu<<<(NACT * 16 + 255) / 256, 256, 0, stream>>>(Y, st + 256, gamma2, beta2,
                                                           X1, (float*)d_out);
}

// Round 6
// 656.360 us; speedup vs baseline: 1.1754x; 1.1754x over previous
//
#include <hip/hip_runtime.h>

#define NACT 200000
#define MPAD 200064          // ceil(NACT/128)*128
#define NBLK 1563            // MPAD/128
#define KOFF 27

#define SCAT_B 21094         // ceil(27*200000/256)
#define CAST_B 25001         // ceil((200000+1)*32/256)
#define PREPW_B 1728         // 27*16384/256

typedef __bf16 bf16x8 __attribute__((ext_vector_type(8)));
typedef __bf16 bf16x4 __attribute__((ext_vector_type(4)));
typedef float f32x4 __attribute__((ext_vector_type(4)));

__device__ __forceinline__ void async_load16(const void* g, void* l) {
  __builtin_amdgcn_global_load_lds(
      (__attribute__((address_space(1))) void*)g,
      (__attribute__((address_space(3))) void*)l, 16, 0, 0);
}

// ---------------- fused prep: rulebook scatter + feature cast + W transpose -------
// G pre-filled with 0x7F7F7F7F sentinel via hipMemsetAsync; GEMM clamps (unsigned)
// to the zero-row. G layout [k][MPAD]: one-touch streaming reads in the GEMM
// (R5's [m][32] transpose thrashed L1/L2: +291MB HBM fetch — reverted).
__global__ void prep_all(const int* __restrict__ ii, const int* __restrict__ oi,
                         int* __restrict__ G,
                         const float* __restrict__ F, __bf16* __restrict__ X,
                         const float* __restrict__ W1, const float* __restrict__ W2,
                         __bf16* __restrict__ T1, __bf16* __restrict__ T2) {
  int b = blockIdx.x;
  if (b < SCAT_B) {
    int i = b * 256 + threadIdx.x;
    if (i < KOFF * NACT) {
      int o = oi[i];
      if (o < NACT) G[(i / NACT) * MPAD + o] = ii[i];  // skip pads (o==NACT)
    }
  } else if (b < SCAT_B + CAST_B) {
    int i = (b - SCAT_B) * 256 + threadIdx.x;
    if (i < (NACT + 1) * 32) {
      float4 v = (i < NACT * 32) ? ((const float4*)F)[i] : make_float4(0.f, 0.f, 0.f, 0.f);
      bf16x4 o = {(__bf16)v.x, (__bf16)v.y, (__bf16)v.z, (__bf16)v.w};
      *(bf16x4*)(X + (i << 2)) = o;
    }
  } else {
    int i = (b - SCAT_B - CAST_B) * 256 + threadIdx.x;   // WT[k][n][c] = W[k][c][n]
    int k = i >> 14, r = i & 16383, n = r >> 7, c = r & 127;
    int src = (k << 14) + (c << 7) + n;
    T1[i] = (__bf16)W1[src];
    T2[i] = (__bf16)W2[src];
  }
}

// ---------------- gather-GEMM: Y[m,:] = sum_k X[G[k][m],:] @ W[k] ----------------
// 128x128 tile, 4 waves (2x2 of 64x64), BK=64, XOR-8 LDS swizzle (R2 structure —
// best measured: ~175us / 43-45% MfmaUtil). New latency tweaks (zero extra bytes):
//   * kk+1 G-line register-prefetched during stage s=0 (hides L2/HBM latency
//     behind one full stage instead of serializing at kk top)
//   * B staging issued before A (B addrs independent of the G result)
__global__ __launch_bounds__(256, 4) void gemm_gather(
    const __bf16* __restrict__ X,   // [NACT+1][128], row NACT = 0
    const __bf16* __restrict__ WT,  // [27][128][128] : WT[k][n][c]
    const int* __restrict__ G,      // [27][MPAD], sentinel-filled
    __bf16* __restrict__ Y,         // [MPAD][128] bf16
    float* __restrict__ Pst)        // [256][NBLK] BN stats partials
{
  __shared__ __bf16 Alds[128 * 64];   // 16 KB
  __shared__ __bf16 Blds[128 * 64];   // 16 KB
  const int t = threadIdx.x;
  const int lane = t & 63;
  const int w = t >> 6;
  const int wm = (w & 1) << 6;
  const int wn = (w >> 1) << 6;
  const int m_base = blockIdx.x << 7;
  const int r0 = t >> 3;   // staging row group 0..31
  const int scb = t & 7;   // lds 16B-chunk slot within row
  const int l15 = lane & 15;
  const int q4 = lane >> 4;

  f32x4 acc[4][4];
#pragma unroll
  for (int i = 0; i < 4; ++i)
#pragma unroll
    for (int j = 0; j < 4; ++j) acc[i][j] = (f32x4){0.f, 0.f, 0.f, 0.f};

  int rowN[4];
#pragma unroll
  for (int j = 0; j < 4; ++j) rowN[j] = G[m_base + r0 + j * 32];   // kk = 0

  for (int kk = 0; kk < KOFF; ++kk) {
    int rowA[4];
#pragma unroll
    for (int j = 0; j < 4; ++j)
      rowA[j] = (unsigned)rowN[j] < NACT ? rowN[j] : NACT;  // pads+sentinel -> zero-row
    const __bf16* wb = WT + (kk << 14);
#pragma unroll
    for (int s = 0; s < 2; ++s) {
      const int c0 = s << 6;
      __syncthreads();   // previous compute finished before LDS overwrite
#pragma unroll
      for (int j = 0; j < 4; ++j) {       // B first: no dependence on G result
        const int r = r0 + j * 32;
        const int gcb = scb ^ (r & 7);    // XOR-swizzle: slot scb <- global chunk gcb
        async_load16(wb + (r << 7) + c0 + (gcb << 3), &Blds[(((r << 3) + scb) << 3)]);
      }
#pragma unroll
      for (int j = 0; j < 4; ++j) {
        const int r = r0 + j * 32;
        const int gcb = scb ^ (r & 7);
        async_load16(X + (rowA[j] << 7) + c0 + (gcb << 3), &Alds[(((r << 3) + scb) << 3)]);
      }
      if (s == 0 && kk + 1 < KOFF) {      // prefetch next kk's G line (streaming)
#pragma unroll
        for (int j = 0; j < 4; ++j) rowN[j] = G[(kk + 1) * MPAD + m_base + r0 + j * 32];
      }
      __syncthreads();   // vmcnt(0) drain for global_load_lds
#pragma unroll
      for (int ks = 0; ks < 2; ++ks) {
        bf16x8 af[4], bfr[4];
        const int cb0 = (ks << 2) + q4;
#pragma unroll
        for (int mi = 0; mi < 4; ++mi) {
          const int r = wm + mi * 16 + l15;
          af[mi] = *(const bf16x8*)&Alds[(((r << 3) + (cb0 ^ (r & 7))) << 3)];
        }
#pragma unroll
        for (int ni = 0; ni < 4; ++ni) {
          const int r = wn + ni * 16 + l15;
          bfr[ni] = *(const bf16x8*)&Blds[(((r << 3) + (cb0 ^ (r & 7))) << 3)];
        }
#pragma unroll
        for (int mi = 0; mi < 4; ++mi)
#pragma unroll
          for (int ni = 0; ni < 4; ++ni)
            acc[mi][ni] = __builtin_amdgcn_mfma_f32_16x16x32_bf16(
                af[mi], bfr[ni], acc[mi][ni], 0, 0, 0);
      }
    }
  }

  // ---- epilogue 1: bf16 Y stores (C/D layout: col=lane&15, row=quad*4+reg) ----
#pragma unroll
  for (int mi = 0; mi < 4; ++mi) {
#pragma unroll
    for (int ni = 0; ni < 4; ++ni) {
      const int col = wn + ni * 16 + l15;
#pragma unroll
      for (int rg = 0; rg < 4; ++rg) {
        const int row = m_base + wm + mi * 16 + (q4 << 2) + rg;
        Y[(row << 7) + col] = (__bf16)acc[mi][ni][rg];
      }
    }
  }

  // ---- epilogue 2: BN stats partials -> Pst (streaming; atomics cost 31MB RMW) ----
  float s[4], s2[4];
#pragma unroll
  for (int ni = 0; ni < 4; ++ni) {
    float a = 0.f, b = 0.f;
#pragma unroll
    for (int mi = 0; mi < 4; ++mi)
#pragma unroll
      for (int rg = 0; rg < 4; ++rg) {
        float v = acc[mi][ni][rg];
        a += v; b += v * v;
      }
    s[ni] = a; s2[ni] = b;
  }
#pragma unroll
  for (int ni = 0; ni < 4; ++ni) {
    s[ni]  += __shfl_xor(s[ni], 16);  s[ni]  += __shfl_xor(s[ni], 32);
    s2[ni] += __shfl_xor(s2[ni], 16); s2[ni] += __shfl_xor(s2[ni], 32);
  }
  float* sc = (float*)Alds;   // 512 floats scratch
  __syncthreads();
  if (q4 == 0) {
#pragma unroll
    for (int ni = 0; ni < 4; ++ni) {
      sc[(w << 6) + ni * 16 + l15]       = s[ni];
      sc[256 + (w << 6) + ni * 16 + l15] = s2[ni];
    }
  }
  __syncthreads();
  {
    const int kind = t >> 7, col = t & 127;
    const int w1 = (col >> 6) << 1;
    const float v = sc[kind * 256 + (w1 << 6) + (col & 63)] +
                    sc[kind * 256 + ((w1 + 1) << 6) + (col & 63)];
    Pst[(size_t)t * NBLK + blockIdx.x] = v;
  }
}

// ---------------- stats tree-reduce fused with BN coeffs ----------------
__global__ void stats_coeffs(const float* __restrict__ P, const float* __restrict__ gamma,
                             const float* __restrict__ beta, float* __restrict__ co) {
  int c = blockIdx.x;  // 0..127
  float s = 0.f, s2 = 0.f;
  for (int i = threadIdx.x; i < NBLK; i += 256) {
    s  += P[(size_t)c * NBLK + i];
    s2 += P[(size_t)(128 + c) * NBLK + i];
  }
  for (int off = 32; off; off >>= 1) {
    s  += __shfl_down(s, off);
    s2 += __shfl_down(s2, off);
  }
  __shared__ float ls[8];
  if ((threadIdx.x & 63) == 0) {
    ls[threadIdx.x >> 6]       = s;
    ls[4 + (threadIdx.x >> 6)] = s2;
  }
  __syncthreads();
  if (threadIdx.x == 0) {
    float S  = ls[0] + ls[1] + ls[2] + ls[3];
    float S2 = ls[4] + ls[5] + ls[6] + ls[7];
    float m = S * (1.f / NACT);
    float v = S2 * (1.f / NACT) - m * m;
    float scale = gamma[c] * rsqrtf(v + 1e-4f);
    co[c] = scale;
    co[128 + c] = beta[c] - m * scale;
  }
}

__global__ void bn_relu_cast(const __bf16* __restrict__ Y, const float* __restrict__ co,
                             __bf16* __restrict__ X2) {
  int i = blockIdx.x * 256 + threadIdx.x;   // 8-elem chunks, (NACT+1)*16
  if (i >= (NACT + 1) * 16) return;
  bf16x8 o;
  if (i < NACT * 16) {
    bf16x8 v = ((const bf16x8*)Y)[i];
    int cg = (i & 15) << 3;
#pragma unroll
    for (int e = 0; e < 8; ++e) {
      float x = fmaf((float)v[e], co[cg + e], co[128 + cg + e]);
      o[e] = (__bf16)fmaxf(x, 0.f);
    }
  } else {
#pragma unroll
    for (int e = 0; e < 8; ++e) o[e] = (__bf16)0.f;   // keep zero-row zero
  }
  ((bf16x8*)X2)[i] = o;
}

__global__ void bn_add_relu(const __bf16* __restrict__ Y, const float* __restrict__ co,
                            const __bf16* __restrict__ Xr, float* __restrict__ O) {
  int i = blockIdx.x * 256 + threadIdx.x;   // 8-elem chunks, NACT*16
  if (i >= NACT * 16) return;
  bf16x8 v = ((const bf16x8*)Y)[i];
  bf16x8 f = ((const bf16x8*)Xr)[i];
  int cg = (i & 15) << 3;
  float4 o0, o1;
  o0.x = fmaxf(fmaf((float)v[0], co[cg + 0], co[128 + cg + 0]) + (float)f[0], 0.f);
  o0.y = fmaxf(fmaf((float)v[1], co[cg + 1], co[128 + cg + 1]) + (float)f[1], 0.f);
  o0.z = fmaxf(fmaf((float)v[2], co[cg + 2], co[128 + cg + 2]) + (float)f[2], 0.f);
  o0.w = fmaxf(fmaf((float)v[3], co[cg + 3], co[128 + cg + 3]) + (float)f[3], 0.f);
  o1.x = fmaxf(fmaf((float)v[4], co[cg + 4], co[128 + cg + 4]) + (float)f[4], 0.f);
  o1.y = fmaxf(fmaf((float)v[5], co[cg + 5], co[128 + cg + 5]) + (float)f[5], 0.f);
  o1.z = fmaxf(fmaf((float)v[6], co[cg + 6], co[128 + cg + 6]) + (float)f[6], 0.f);
  o1.w = fmaxf(fmaf((float)v[7], co[cg + 7], co[128 + cg + 7]) + (float)f[7], 0.f);
  ((float4*)O)[2 * i] = o0;
  ((float4*)O)[2 * i + 1] = o1;
}

// ---------------- launcher ----------------
extern "C" void kernel_launch(void* const* d_in, const int* in_sizes, int n_in,
                              void* d_out, int out_size, void* d_ws, size_t ws_size,
                              hipStream_t stream) {
  const float* features = (const float*)d_in[0];
  const float* W1       = (const float*)d_in[1];
  const float* gamma1   = (const float*)d_in[2];
  const float* beta1    = (const float*)d_in[3];
  const float* W2       = (const float*)d_in[4];
  const float* gamma2   = (const float*)d_in[5];
  const float* beta2    = (const float*)d_in[6];
  const int* in_idx     = (const int*)d_in[7];
  const int* out_idx    = (const int*)d_in[8];

  char* ws = (char*)d_ws;
  size_t off = 0;
  int*    G   = (int*)(ws + off);    off += (size_t)KOFF * MPAD * 4;          // 21.6 MB
  __bf16* X1  = (__bf16*)(ws + off); off += (size_t)(NACT + 1) * 128 * 2;     // 51.2 MB
  __bf16* X2  = (__bf16*)(ws + off); off += (size_t)(NACT + 1) * 128 * 2;     // 51.2 MB
  __bf16* T1  = (__bf16*)(ws + off); off += (size_t)KOFF * 128 * 128 * 2;     // 0.88 MB
  __bf16* T2  = (__bf16*)(ws + off); off += (size_t)KOFF * 128 * 128 * 2;     // 0.88 MB
  __bf16* Y   = (__bf16*)(ws + off); off += (size_t)MPAD * 128 * 2;           // 51.2 MB
  float*  Pst = (float*)(ws + off);  off += (size_t)256 * NBLK * 4;           // 1.6 MB
  float*  st  = (float*)(ws + off);  off += 4096;   // coeffs1 @0, coeffs2 @256

  hipMemsetAsync(G, 0x7F, (size_t)KOFF * MPAD * 4, stream);  // sentinel >= NACT

  prep_all<<<SCAT_B + CAST_B + PREPW_B, 256, 0, stream>>>(
      in_idx, out_idx, G, features, X1, W1, W2, T1, T2);

  gemm_gather<<<NBLK, 256, 0, stream>>>(X1, T1, G, Y, Pst);
  stats_coeffs<<<128, 256, 0, stream>>>(Pst, gamma1, beta1, st);
  bn_relu_cast<<<((NACT + 1) * 16 + 255) / 256, 256, 0, stream>>>(Y, st, X2);

  gemm_gather<<<NBLK, 256, 0, stream>>>(X2, T2, G, Y, Pst);
  stats_coeffs<<<128, 256, 0, stream>>>(Pst, gamma2, beta2, st + 256);
  bn_add_relu<<<(NACT * 16 + 255) / 256, 256, 0, stream>>>(Y, st + 256, X1, (float*)d_out);
}